// Round 1
// 96.709 us; speedup vs baseline: 1.1822x; 1.1822x over previous
//
#include <hip/hip_runtime.h>
#include <math.h>

// RoutingCapsules — B=16, I=2048, K=64, J=64, D=32, 3 routing iters.
// u_hat[b,j,i,d] = sum_k W[j,d,k] x[b,i,k] is never materialized:
//   s[b,j,d]  = sum_k W[j,d,k] y[b,j,k],    y[b,j,k]  = sum_i c[b,j,i] x[b,i,k]
//   uv[b,j,i] = sum_k x[b,i,k] wv[b,j,k],   wv[b,j,k] = sum_d W[j,d,k] v[b,j,d]
// Iter-1 c is uniform -> y1[b,j,k] = ybar[b,k]  (j-independent).
// Logits are LINEAR in wv:  b2 = uv1+uv2 = x·(wv1+wv2)  -> no logit buffer.
//
// R2 changes (latency/occupancy attack — we are far from both rooflines):
//  * caps: grid (16,4)->(16,16), ONE j per wave (4x thread parallelism),
//    float4 global loads for W and ypart (4 tiles in flight / instr),
//    all-64-lane s-compute (k halves + shfl_xor(32)).
//  * route: LDS re-layout so BOTH inner GEMMs read float4 (ds_read_b128):
//    x_smT[k][i] + wv_smT[k][j] for the uv loop, c stored transposed as
//    uv_smT[j][i] so the ypart loop is contiguous in i for c AND x.
//    Softmax keeps its 16 values in registers between passes.
//  * ybar: float4 loads.

#define BB 16
#define II 2048
#define KK 64
#define JJ 64
#define DD 32
#define ITILE 64
#define NT (II / ITILE)   // 32 i-tiles
#define YB 16             // ybar partial chunks

// ---------------------------------------------------------------------------
// ybar partials: ybarp[b][q][k] = (1/64) sum_{i in chunk q (128 rows)} x[b,i,k]
// grid (16,16), 256 thr, float4 loads. caps<0> sums the 16 partials.
// ---------------------------------------------------------------------------
__global__ __launch_bounds__(256) void ybar_kernel(const float* __restrict__ x,
                                                   float* __restrict__ ybarp) {
    const int b = blockIdx.x;
    const int q = blockIdx.y;
    const int tid = threadIdx.x;
    const int kq = tid & 15;     // float4 column
    const int r  = tid >> 4;     // 0..15 row group
    const float4* xp = (const float4*)(x + ((size_t)b * II + (size_t)q * 128) * KK) + kq;
    float4 a = make_float4(0.f, 0.f, 0.f, 0.f);
    #pragma unroll
    for (int n = 0; n < 8; ++n) {
        const float4 v = xp[(size_t)(r + n * 16) * 16];
        a.x += v.x; a.y += v.y; a.z += v.z; a.w += v.w;
    }
    __shared__ float4 sm[16][17];
    sm[r][kq] = a;
    __syncthreads();
    if (tid < 64) {
        const float* smf = (const float*)sm;   // row stride 68 floats
        float s = 0.f;
        #pragma unroll
        for (int rr = 0; rr < 16; ++rr) s += smf[rr * 68 + tid];
        ybarp[(b * YB + q) * KK + tid] = s * (1.0f / 64.0f);
    }
}

// ---------------------------------------------------------------------------
// caps kernel: per (b,j): s[d] = sum_k W[j,d,k] y[b,j,k]; v = squash(s);
//   MODE 0: y = sum of ybar partials (j-independent); wv  = W^T v      (wv1)
//   MODE 1: y = sum_t ypart;                          wv += W^T v      (wv1+wv2)
//   MODE 2: y = sum_t ypart;                          out = squash(s)
// grid (16,16); 4 waves/block, each wave owns ONE j. All LDS wave-private ->
// no __syncthreads anywhere.
// ---------------------------------------------------------------------------
template <int MODE>
__global__ __launch_bounds__(256) void caps_kernel(const float* __restrict__ W,
                                                   const float* __restrict__ ybarp,
                                                   const float* __restrict__ ypart,
                                                   float* __restrict__ wv,
                                                   float* __restrict__ out) {
    const int b = blockIdx.x;
    const int jq = blockIdx.y;          // 0..15
    const int tid = threadIdx.x;
    const int w = tid >> 6;
    const int lane = tid & 63;
    const int j = jq * 4 + w;           // one j per wave

    __shared__ alignas(16) float W_sm[4][DD][68];   // stride 68: 16B-aligned rows
    __shared__ alignas(16) float y_sm[4][KK];
    __shared__ float v_sm[4][DD];

    // ---- W[j] (32x64) -> LDS, float4 global loads (8 per lane) ----
    const float* Wp = W + (size_t)j * DD * KK;
    #pragma unroll
    for (int rr = 0; rr < 8; ++rr) {
        const int idx = rr * 64 + lane;          // 0..511
        const int d = idx >> 4, kq = idx & 15;
        *(float4*)&W_sm[w][d][kq * 4] = *(const float4*)(Wp + d * KK + kq * 4);
    }

    // ---- y[k] ----
    if (MODE == 0) {
        const float* yp = ybarp + (size_t)b * YB * KK + lane;
        float a = 0.f;
        #pragma unroll
        for (int t = 0; t < YB; ++t) a += yp[(size_t)t * KK];
        y_sm[w][lane] = a;
    } else {
        const int kq = lane & 15, th = lane >> 4;   // 4-way split over tiles
        float4 a = make_float4(0.f, 0.f, 0.f, 0.f);
        #pragma unroll
        for (int n = 0; n < 8; ++n) {
            const int t = th + n * 4;
            const float4 v = *(const float4*)(ypart +
                (((size_t)b * NT + t) * JJ + j) * KK + kq * 4);
            a.x += v.x; a.y += v.y; a.z += v.z; a.w += v.w;
        }
        a.x += __shfl_xor(a.x, 16, 64); a.y += __shfl_xor(a.y, 16, 64);
        a.z += __shfl_xor(a.z, 16, 64); a.w += __shfl_xor(a.w, 16, 64);
        a.x += __shfl_xor(a.x, 32, 64); a.y += __shfl_xor(a.y, 32, 64);
        a.z += __shfl_xor(a.z, 32, 64); a.w += __shfl_xor(a.w, 32, 64);
        if (lane < 16) *(float4*)&y_sm[w][kq * 4] = a;
    }

    // ---- s[d] = sum_k W[d][k] y[k] — all 64 lanes: d = lane&31, k-half split ----
    const int d = lane & 31;
    const int kh = (lane >> 5) * 32;
    float sv = 0.f;
    #pragma unroll
    for (int kq = 0; kq < 8; ++kq) {
        const float4 wr = *(const float4*)&W_sm[w][d][kh + kq * 4];
        const float4 yr = *(const float4*)&y_sm[w][kh + kq * 4];
        sv += wr.x * yr.x + wr.y * yr.y + wr.z * yr.z + wr.w * yr.w;
    }
    sv += __shfl_xor(sv, 32, 64);            // full s[d] in every lane

    float ps = sv * sv;
    #pragma unroll
    for (int m = 1; m < 32; m <<= 1) ps += __shfl_xor(ps, m, 64);
    const float f = ps / ((1.f + ps) * (sqrtf(ps) + 1e-8f));   // squash factor

    if (MODE == 2) {
        if (lane < DD) out[((size_t)b * JJ + j) * DD + lane] = sv * f;
    } else {
        if (lane < DD) v_sm[w][lane] = sv * f;
        float a = 0.f;
        #pragma unroll
        for (int dd = 0; dd < DD; ++dd) a += W_sm[w][dd][lane] * v_sm[w][dd];
        const size_t idx = ((size_t)b * JJ + j) * KK + lane;
        if (MODE == 1) a += wv[idx];
        wv[idx] = a;
    }
}

// ---------------------------------------------------------------------------
// route kernel (both passes): per (b, i-tile of 64):
//   uv[i,j] = sum_k x[i,k] wv[j,k];  c = softmax_j(uv);
//   ypart[b,t,j,k] = sum_{i in tile} c[i,j] x[i,k]
// grid (16,32), 256 thr. LDS layouts chosen so both GEMM loops use b128 reads:
//   x_smT[k][i], wv_smT[k][j] (uv loop), uv_smT[j][i] (c, ypart loop).
// ---------------------------------------------------------------------------
__global__ __launch_bounds__(256) void route_kernel(const float* __restrict__ x,
                                                    const float* __restrict__ wv,
                                                    float* __restrict__ ypart) {
    const int b = blockIdx.x;
    const int t = blockIdx.y;
    const int tid = threadIdx.x;
    const int i0 = t * ITILE;

    __shared__ alignas(16) float x_smT[KK][68];    // [k][i]
    __shared__ alignas(16) float wv_smT[KK][68];   // [k][j]
    __shared__ alignas(16) float uv_smT[JJ][68];   // [j][i] -> later c[j][i]
    __shared__ float red[8][72];                   // per-wave max / expsum

    // stage x tile (transposed) and wv (transposed) — float4 global reads
    const float4* x4 = (const float4*)(x + ((size_t)b * II + i0) * KK);
    #pragma unroll
    for (int n = 0; n < 4; ++n) {
        const int idx = tid + n * 256;             // 64i x 16kq
        const int i = idx >> 4, kq = idx & 15;
        const float4 v = x4[idx];
        x_smT[kq * 4 + 0][i] = v.x;
        x_smT[kq * 4 + 1][i] = v.y;
        x_smT[kq * 4 + 2][i] = v.z;
        x_smT[kq * 4 + 3][i] = v.w;
    }
    const float4* wv4 = (const float4*)(wv + (size_t)b * JJ * KK);
    #pragma unroll
    for (int n = 0; n < 4; ++n) {
        const int idx = tid + n * 256;             // 64j x 16kq
        const int jj = idx >> 4, kq = idx & 15;
        const float4 v = wv4[idx];
        wv_smT[kq * 4 + 0][jj] = v.x;
        wv_smT[kq * 4 + 1][jj] = v.y;
        wv_smT[kq * 4 + 2][jj] = v.z;
        wv_smT[kq * 4 + 3][jj] = v.w;
    }
    __syncthreads();

    // ---- uv[j][i] = sum_k x[i][k] wv[j][k], 4i x 4j per thread, b128 reads ----
    {
        const int ib = (tid & 15) * 4, jb = (tid >> 4) * 4;
        float acc[4][4] = {};   // [c(i)][r(j)]
        for (int k = 0; k < KK; ++k) {
            const float4 xv = *(const float4*)&x_smT[k][ib];
            const float4 wvv = *(const float4*)&wv_smT[k][jb];
            acc[0][0] += xv.x * wvv.x; acc[0][1] += xv.x * wvv.y;
            acc[0][2] += xv.x * wvv.z; acc[0][3] += xv.x * wvv.w;
            acc[1][0] += xv.y * wvv.x; acc[1][1] += xv.y * wvv.y;
            acc[1][2] += xv.y * wvv.z; acc[1][3] += xv.y * wvv.w;
            acc[2][0] += xv.z * wvv.x; acc[2][1] += xv.z * wvv.y;
            acc[2][2] += xv.z * wvv.z; acc[2][3] += xv.z * wvv.w;
            acc[3][0] += xv.w * wvv.x; acc[3][1] += xv.w * wvv.y;
            acc[3][2] += xv.w * wvv.z; acc[3][3] += xv.w * wvv.w;
        }
        #pragma unroll
        for (int r = 0; r < 4; ++r)
            *(float4*)&uv_smT[jb + r][ib] =
                make_float4(acc[0][r], acc[1][r], acc[2][r], acc[3][r]);
    }
    __syncthreads();

    // ---- softmax over j (down the columns); 16 values live in registers ----
    {
        const int i = tid & 63;
        const int w = tid >> 6;
        const int j0 = w * 16;
        float e[16];
        float m = -1e30f;
        #pragma unroll
        for (int jj = 0; jj < 16; ++jj) {
            e[jj] = uv_smT[j0 + jj][i];
            m = fmaxf(m, e[jj]);
        }
        red[w][i] = m;
        __syncthreads();
        m = fmaxf(fmaxf(red[0][i], red[1][i]), fmaxf(red[2][i], red[3][i]));
        float s = 0.f;
        #pragma unroll
        for (int jj = 0; jj < 16; ++jj) {
            e[jj] = __expf(e[jj] - m);
            s += e[jj];
        }
        red[4 + w][i] = s;
        __syncthreads();
        const float inv = 1.f / (red[4][i] + red[5][i] + red[6][i] + red[7][i]);
        #pragma unroll
        for (int jj = 0; jj < 16; ++jj) uv_smT[j0 + jj][i] = e[jj] * inv;
    }
    __syncthreads();

    // ---- ypart[j][k] = sum_i c[j][i] x[k][i]: 4j x 4k per thread, b128 reads.
    //      j-rows = a+16r (consecutive per instr -> conflict-free) ----
    {
        const int a = tid & 15;       // j base
        const int kb = (tid >> 4) * 4;
        float acc[4][4] = {};         // [r(j)][c(k)]
        for (int i = 0; i < ITILE; i += 4) {
            float4 xv[4];
            #pragma unroll
            for (int c = 0; c < 4; ++c) xv[c] = *(const float4*)&x_smT[kb + c][i];
            #pragma unroll
            for (int r = 0; r < 4; ++r) {
                const float4 cv = *(const float4*)&uv_smT[a + 16 * r][i];
                #pragma unroll
                for (int c = 0; c < 4; ++c)
                    acc[r][c] += cv.x * xv[c].x + cv.y * xv[c].y +
                                 cv.z * xv[c].z + cv.w * xv[c].w;
            }
        }
        float* yp = ypart + ((size_t)b * NT + t) * JJ * KK;
        #pragma unroll
        for (int r = 0; r < 4; ++r)
            *(float4*)&yp[(a + 16 * r) * KK + kb] =
                make_float4(acc[r][0], acc[r][1], acc[r][2], acc[r][3]);
    }
}

// ---------------------------------------------------------------------------
// Workspace (floats): wv[65536] | ybarp[16384] | ypart[2097152]  (~8.7 MB)
// No memset needed — every buffer is fully written before it is read.
// ---------------------------------------------------------------------------
extern "C" void kernel_launch(void* const* d_in, const int* in_sizes, int n_in,
                              void* d_out, int out_size, void* d_ws, size_t ws_size,
                              hipStream_t stream) {
    const float* x = (const float*)d_in[0];
    const float* W = (const float*)d_in[1];
    float* out = (float*)d_out;
    float* ws = (float*)d_ws;

    float* wv    = ws;                    // 65536
    float* ybarp = ws + 65536;            // 16384
    float* ypart = ws + 65536 + 16384;    // 2097152

    ybar_kernel<<<dim3(BB, YB), 256, 0, stream>>>(x, ybarp);
    caps_kernel<0><<<dim3(BB, 16), 256, 0, stream>>>(W, ybarp, ypart, wv, out); // wv1
    route_kernel<<<dim3(BB, NT), 256, 0, stream>>>(x, wv, ypart);               // c2 -> y2 partials
    caps_kernel<1><<<dim3(BB, 16), 256, 0, stream>>>(W, ybarp, ypart, wv, out); // wv = wv1+wv2
    route_kernel<<<dim3(BB, NT), 256, 0, stream>>>(x, wv, ypart);               // c3 -> y3 partials
    caps_kernel<2><<<dim3(BB, 16), 256, 0, stream>>>(W, ybarp, ypart, wv, out); // out = squash(s3)
}